// Round 7
// baseline (249.944 us; speedup 1.0000x reference)
//
#include <hip/hip_runtime.h>
#include <hip/hip_bf16.h>
#include <stdint.h>

#define DM   1024
#define DKV  64
#define HEADS 16
#define BATCH 2
#define SEQ  2048
#define BS   (BATCH*SEQ)    // 4096
#define BHD  (BATCH*HEADS)  // 32

typedef __attribute__((ext_vector_type(8))) short bf16x8;
typedef __attribute__((ext_vector_type(4))) short bf16x4;
typedef __attribute__((ext_vector_type(4))) float f32x4;

// ---------- helpers ----------
__device__ inline unsigned fb(float f) { union { float f; unsigned u; } v; v.f = f; return v.u; }

__device__ inline unsigned short bf16_rtn(float f) {
  unsigned u = fb(f);
  unsigned r = u + 0x7fffu + ((u >> 16) & 1u);
  return (unsigned short)(r >> 16);
}
__device__ inline float bf16_to_f(unsigned short h) {
  union { unsigned u; float f; } v; v.u = ((unsigned)h) << 16; return v.f;
}
// split x ≈ hi + lo, |lo| <= 2^-9 |x|, residual ~2^-18
__device__ inline void split_bf16(float x, unsigned short& hi, unsigned short& lo) {
  hi = bf16_rtn(x);
  lo = bf16_rtn(x - bf16_to_f(hi));
}
// pack two fp32 -> two bf16 (round-half-up) in one dword via v_perm_b32
__device__ inline unsigned pack2_bf16(float lo_elem, float hi_elem) {
  return __builtin_amdgcn_perm(fb(hi_elem) + 0x8000u, fb(lo_elem) + 0x8000u, 0x07060302u);
}

__device__ inline float fast_exp2(float x) {
#if __has_builtin(__builtin_amdgcn_exp2f)
  return __builtin_amdgcn_exp2f(x);
#else
  return exp2f(x);
#endif
}

__device__ inline f32x4 mfma16x16x16_bf16(bf16x4 a, bf16x4 b, f32x4 c) {
#if __has_builtin(__builtin_amdgcn_mfma_f32_16x16x16bf16_1k)
  return __builtin_amdgcn_mfma_f32_16x16x16bf16_1k(a, b, c, 0, 0, 0);
#else
  asm volatile("v_mfma_f32_16x16x16_bf16 %0, %1, %2, %0" : "+v"(c) : "v"(a), "v"(b));
  return c;
#endif
}

// stage 16B/lane: async direct-to-LDS (dest = wave-uniform base + lane*16)
__device__ inline void stage16(const unsigned short* g, unsigned short* lds_base, int lane) {
#if __has_builtin(__builtin_amdgcn_global_load_lds)
  __builtin_amdgcn_global_load_lds((__attribute__((address_space(1))) void*)(g),
                                   (__attribute__((address_space(3))) void*)(lds_base),
                                   16, 0, 0);
#else
  *(bf16x8*)(lds_base + lane * 8) = *(const bf16x8*)g;
#endif
}

// XOR-swizzled LDS index for a 64-col bf16 tile (8 chunks of 8 shorts per row)
__device__ inline int swz(int row, int chunk) {
  return row * 64 + (((chunk ^ (row & 7)) & 7) << 3);
}

// ---------- fused prep: blocks [0,2048) cvt_x_split, [2048,2816) pack_qkv_split,
// ---------- [2816,3072) pack_wo.  One dispatch instead of three (saves 2 gaps).
__global__ void prep(const float* __restrict__ x,
                     const float* __restrict__ Wq, const float* __restrict__ Wk,
                     const float* __restrict__ Wv, const float* __restrict__ Wo,
                     unsigned short* __restrict__ xh, unsigned short* __restrict__ xl,
                     unsigned short* __restrict__ Wh, unsigned short* __restrict__ Wl,
                     unsigned short* __restrict__ WoT) {
  __shared__ float tile[64][65];
  const int bid = blockIdx.x;
  const int t = threadIdx.x;

  if (bid < 2048) {
    // ---- cvt_x_split ----
    int i = (bid * 256 + t) * 8;
    bf16x8 oh, ol;
    #pragma unroll
    for (int j = 0; j < 8; ++j) {
      unsigned short hi, lo;
      split_bf16(x[i + j], hi, lo);
      oh[j] = (short)hi; ol[j] = (short)lo;
    }
    *(bf16x8*)(xh + i) = oh;
    *(bf16x8*)(xl + i) = ol;
    return;
  }
  if (bid < 2816) {
    // ---- pack_qkv_split: b2 = p*256 + h*16 + mt ----
    int b2 = bid - 2048;
    int p = b2 >> 8, h = (b2 >> 4) & 15, mt = b2 & 15;
    const float* W = (p == 0) ? Wq : (p == 1) ? Wk : Wv;
    const float* src = W + (size_t)h * (DM * DKV);
    int m0 = mt * 64;
    #pragma unroll
    for (int pass = 0; pass < 16; ++pass) {
      int row = pass * 4 + (t >> 6), col = t & 63;
      tile[row][col] = src[(size_t)(m0 + row) * DKV + col];
    }
    __syncthreads();
    int cbase = p * 1024 + h * 64;
    #pragma unroll
    for (int pass = 0; pass < 16; ++pass) {
      int krow = pass * 4 + (t >> 6), mcol = t & 63;
      unsigned short hi, lo;
      split_bf16(tile[mcol][krow], hi, lo);
      size_t idx = (size_t)(cbase + krow) * DM + m0 + mcol;
      Wh[idx] = hi; Wl[idx] = lo;
    }
    return;
  }
  {
    // ---- pack_wo: b3 = ib*16 + jb ----
    int b3 = bid - 2816;
    int ib = b3 >> 4, jb = b3 & 15;
    #pragma unroll
    for (int pass = 0; pass < 16; ++pass) {
      int row = pass * 4 + (t >> 6), col = t & 63;
      tile[row][col] = Wo[(size_t)(ib * 64 + row) * DM + jb * 64 + col];
    }
    __syncthreads();
    #pragma unroll
    for (int pass = 0; pass < 16; ++pass) {
      int a = pass * 4 + (t >> 6), b = t & 63;
      WoT[(size_t)(jb * 64 + a) * DM + ib * 64 + b] = bf16_rtn(tile[b][a]);
    }
  }
}

// ---------- fused gemm_qkv: blocks 0..511 do x@Wqk^T (split, 128x128), ----------
// ---------- blocks 512..1023 do x@Wv^T (64x128) -> Vt. One dispatch:  ----------
// ---------- V blocks back-fill CUs while QK blocks drain.             ----------
__global__ __launch_bounds__(256, 2)
void gemm_qkv(const unsigned short* __restrict__ Ah, const unsigned short* __restrict__ Al,
              const unsigned short* __restrict__ Bh, const unsigned short* __restrict__ Bl,
              unsigned short* __restrict__ Qh, unsigned short* __restrict__ Ql,
              unsigned short* __restrict__ Kh, unsigned short* __restrict__ Kl,
              unsigned short* __restrict__ Vt) {
  __shared__ unsigned short smem[32768];   // 64 KB
  const int tid = threadIdx.x;
  const int w = tid >> 6, lane = tid & 63;
  const int quad = lane >> 4, l16 = lane & 15;
  const int wm = w >> 1, wn = w & 1;
  const int bid = blockIdx.x;
  const int r8 = lane >> 3, c8 = lane & 7;
  const int cs = c8 ^ r8;

  if (bid < 512) {
    // ---- QK half: tile 128x128, BK=64, split-precision (3 MFMA/frag) ----
    unsigned short* AsH = smem;            // 8192 shorts
    unsigned short* AsL = smem + 8192;
    unsigned short* BsH = smem + 16384;
    unsigned short* BsL = smem + 24576;
    const int bn = bid & 15, bm = bid >> 4;

    f32x4 acc[4][4];
    #pragma unroll
    for (int i = 0; i < 4; ++i)
      #pragma unroll
      for (int j = 0; j < 4; ++j) acc[i][j] = (f32x4){0.f, 0.f, 0.f, 0.f};

    const size_t offA = (size_t)(bm * 128 + w * 32 + r8) * DM + cs * 8;
    const size_t offB = (size_t)(bn * 128 + w * 32 + r8) * DM + cs * 8;

    for (int kk = 0; kk < DM / 64; ++kk) {
      #pragma unroll
      for (int ps = 0; ps < 4; ++ps) {
        stage16(Ah + offA + kk * 64 + ps * 8 * DM, AsH + (w * 32 + ps * 8) * 64, lane);
        stage16(Al + offA + kk * 64 + ps * 8 * DM, AsL + (w * 32 + ps * 8) * 64, lane);
        stage16(Bh + offB + kk * 64 + ps * 8 * DM, BsH + (w * 32 + ps * 8) * 64, lane);
        stage16(Bl + offB + kk * 64 + ps * 8 * DM, BsL + (w * 32 + ps * 8) * 64, lane);
      }
      asm volatile("s_waitcnt vmcnt(0)" ::: "memory");
      __syncthreads();
      #pragma unroll
      for (int ks = 0; ks < 2; ++ks) {
        bf16x8 afh[4], afl[4], bfh[4], bfl[4];
        #pragma unroll
        for (int mt = 0; mt < 4; ++mt) {
          int row = wm * 64 + mt * 16 + l16;
          int ad = row * 64 + ((((ks * 4 + quad) ^ (row & 7)) & 7) << 3);
          afh[mt] = *(const bf16x8*)(AsH + ad);
          afl[mt] = *(const bf16x8*)(AsL + ad);
        }
        #pragma unroll
        for (int nt = 0; nt < 4; ++nt) {
          int row = wn * 64 + nt * 16 + l16;
          int ad = row * 64 + ((((ks * 4 + quad) ^ (row & 7)) & 7) << 3);
          bfh[nt] = *(const bf16x8*)(BsH + ad);
          bfl[nt] = *(const bf16x8*)(BsL + ad);
        }
        #pragma unroll
        for (int mt = 0; mt < 4; ++mt)
          #pragma unroll
          for (int nt = 0; nt < 4; ++nt) {
            acc[mt][nt] = __builtin_amdgcn_mfma_f32_16x16x32_bf16(afh[mt], bfh[nt], acc[mt][nt], 0, 0, 0);
            acc[mt][nt] = __builtin_amdgcn_mfma_f32_16x16x32_bf16(afh[mt], bfl[nt], acc[mt][nt], 0, 0, 0);
            acc[mt][nt] = __builtin_amdgcn_mfma_f32_16x16x32_bf16(afl[mt], bfh[nt], acc[mt][nt], 0, 0, 0);
          }
      }
      __syncthreads();
    }

    const float SCL = 0.18033688011112042f;  // (1/sqrt(64)) * log2(e), folded into Q
    #pragma unroll
    for (int mt = 0; mt < 4; ++mt) {
      int m_g = bm * 128 + wm * 64 + mt * 16 + quad * 4;
      #pragma unroll
      for (int nt = 0; nt < 4; ++nt) {
        int n_g = bn * 128 + wn * 64 + nt * 16 + l16;
        int p = n_g >> 10, h = (n_g >> 6) & 15, k = n_g & 63;
        #pragma unroll
        for (int r = 0; r < 4; ++r) {
          int row = m_g + r;
          int b = row >> 11, s = row & 2047;
          int bh = b * HEADS + h;
          float v = acc[mt][nt][r];
          size_t idx = ((size_t)(bh * SEQ + s)) * DKV + k;
          unsigned short hi, lo;
          if (p == 0) {
            split_bf16(v * SCL, hi, lo);
            Qh[idx] = hi; Ql[idx] = lo;
          } else {
            split_bf16(v, hi, lo);
            Kh[idx] = hi; Kl[idx] = lo;
          }
        }
      }
    }
  } else {
    // ---- V half: plain bf16, tile 64x128 -> Vt transposed ----
    unsigned short* As = smem;             // 4096 shorts
    unsigned short* Bs = smem + 4096;      // 8192 shorts
    const int vid = bid - 512;
    const int bn = vid & 7, bm = vid >> 3;
    const unsigned short* Bt = Bh + (size_t)2048 * DM;   // V weight rows of WcatT (hi)

    f32x4 acc[2][4];
    #pragma unroll
    for (int i = 0; i < 2; ++i)
      #pragma unroll
      for (int j = 0; j < 4; ++j) acc[i][j] = (f32x4){0.f, 0.f, 0.f, 0.f};

    const size_t offA = (size_t)(bm * 64 + w * 16 + r8) * DM + cs * 8;
    const size_t offB = (size_t)(bn * 128 + w * 32 + r8) * DM + cs * 8;

    for (int kk = 0; kk < DM / 64; ++kk) {
      #pragma unroll
      for (int ps = 0; ps < 2; ++ps)
        stage16(Ah + offA + kk * 64 + ps * 8 * DM, As + (w * 16 + ps * 8) * 64, lane);
      #pragma unroll
      for (int ps = 0; ps < 4; ++ps)
        stage16(Bt + offB + kk * 64 + ps * 8 * DM, Bs + (w * 32 + ps * 8) * 64, lane);
      asm volatile("s_waitcnt vmcnt(0)" ::: "memory");
      __syncthreads();
      #pragma unroll
      for (int ks = 0; ks < 2; ++ks) {
        bf16x8 af[2], bfr[4];
        #pragma unroll
        for (int mt = 0; mt < 2; ++mt) {
          int row = wm * 32 + mt * 16 + l16;
          af[mt] = *(const bf16x8*)(As + row * 64 + ((((ks * 4 + quad) ^ (row & 7)) & 7) << 3));
        }
        #pragma unroll
        for (int nt = 0; nt < 4; ++nt) {
          int row = wn * 64 + nt * 16 + l16;
          bfr[nt] = *(const bf16x8*)(Bs + row * 64 + ((((ks * 4 + quad) ^ (row & 7)) & 7) << 3));
        }
        #pragma unroll
        for (int mt = 0; mt < 2; ++mt)
          #pragma unroll
          for (int nt = 0; nt < 4; ++nt)
            acc[mt][nt] = __builtin_amdgcn_mfma_f32_16x16x32_bf16(af[mt], bfr[nt], acc[mt][nt], 0, 0, 0);
      }
      __syncthreads();
    }

    #pragma unroll
    for (int mt = 0; mt < 2; ++mt) {
      int m_g = bm * 64 + wm * 32 + mt * 16 + quad * 4;
      #pragma unroll
      for (int nt = 0; nt < 4; ++nt) {
        int n_g = bn * 128 + wn * 64 + nt * 16 + l16;   // 0..1023 within V block
        int h = n_g >> 6, k = n_g & 63;
        #pragma unroll
        for (int r = 0; r < 4; ++r) {
          int row = m_g + r;
          int b = row >> 11, s = row & 2047;
          int bh = b * HEADS + h;
          Vt[((size_t)(bh * DKV + k)) * SEQ + s] = bf16_rtn(acc[mt][nt][r]);
        }
      }
    }
  }
}

// ---------- flash: pipelined + defer-max softmax + hoisted PV loads ----------
// 256 threads, 4 waves, 32 q-rows/wave (qt=2); K hi/lo + V double-buffered (48 KB).
// PV's 16 ds_read_b64 are hoisted to the TOP of the iteration body (V[cb] is
// stable all iteration): LDS latency hides under softmax exp2 + QK MFMA.
__global__ __launch_bounds__(256, 2)
void flash(const unsigned short* __restrict__ Qh, const unsigned short* __restrict__ Ql,
           const unsigned short* __restrict__ Kh, const unsigned short* __restrict__ Kl,
           const unsigned short* __restrict__ Vt, unsigned short* __restrict__ ctx) {
  __shared__ unsigned short KtH[2][64 * 64], KtL[2][64 * 64], Vts[2][64 * 64];
  const int tid = threadIdx.x;
  const int w = tid >> 6, lane = tid & 63, quad = lane >> 4, l16 = lane & 15;
  const int bh = blockIdx.x;
  const int q0 = blockIdx.y * 128;

  // Q B-frags (scaled by SCL already): [n=q][k=d], split hi/lo
  bf16x8 qfh[2][2], qfl[2][2];
  #pragma unroll
  for (int qt = 0; qt < 2; ++qt) {
    int qrow = q0 + w * 32 + qt * 16 + l16;
    size_t base = ((size_t)(bh * SEQ + qrow)) * DKV + quad * 8;
    qfh[qt][0] = *(const bf16x8*)(Qh + base);
    qfh[qt][1] = *(const bf16x8*)(Qh + base + 32);
    qfl[qt][0] = *(const bf16x8*)(Ql + base);
    qfl[qt][1] = *(const bf16x8*)(Ql + base + 32);
  }

  float m_run[2] = {-1e30f, -1e30f};
  float l_run[2] = {0.f, 0.f};          // PER-LANE partial sums
  f32x4 acc[2][4];
  #pragma unroll
  for (int qt = 0; qt < 2; ++qt)
    #pragma unroll
    for (int vt = 0; vt < 4; ++vt) acc[qt][vt] = (f32x4){0.f, 0.f, 0.f, 0.f};

  const int srow = w * 16 + (lane >> 3);
  const int csrc = (lane & 7) ^ (lane >> 3);
  const unsigned short* kh_src = Kh + ((size_t)(bh * SEQ) + srow) * DKV + csrc * 8;
  const unsigned short* kl_src = Kl + ((size_t)(bh * SEQ) + srow) * DKV + csrc * 8;
  const unsigned short* v_src  = Vt + ((size_t)(bh * DKV) + srow) * SEQ + csrc * 8;

  #define STAGE_K(buf, kt0)                                                     \
    do {                                                                        \
      unsigned short* dH = &KtH[buf][(w * 16) * 64];                            \
      unsigned short* dL = &KtL[buf][(w * 16) * 64];                            \
      stage16(kh_src + (size_t)(kt0) * 64 * DKV,           dH,       lane);     \
      stage16(kh_src + (size_t)(kt0) * 64 * DKV + 8 * DKV, dH + 512, lane);     \
      stage16(kl_src + (size_t)(kt0) * 64 * DKV,           dL,       lane);     \
      stage16(kl_src + (size_t)(kt0) * 64 * DKV + 8 * DKV, dL + 512, lane);     \
    } while (0)
  #define STAGE_V(buf, kt0)                                                     \
    do {                                                                        \
      unsigned short* dV = &Vts[buf][(w * 16) * 64];                            \
      stage16(v_src + (kt0) * 64,           dV,       lane);                    \
      stage16(v_src + (kt0) * 64 + 8 * SEQ, dV + 512, lane);                    \
    } while (0)

  #define QK_HALF(STV, KHP, KLP, MT0)                                           \
    _Pragma("unroll")                                                           \
    for (int mt = (MT0); mt < (MT0) + 2; ++mt) {                                \
      int rowA = mt * 16 + l16;                                                 \
      bf16x8 kah0 = *(const bf16x8*)((KHP) + swz(rowA, quad));                  \
      bf16x8 kah1 = *(const bf16x8*)((KHP) + swz(rowA, quad + 4));              \
      bf16x8 kal0 = *(const bf16x8*)((KLP) + swz(rowA, quad));                  \
      bf16x8 kal1 = *(const bf16x8*)((KLP) + swz(rowA, quad + 4));              \
      _Pragma("unroll")                                                         \
      for (int qt = 0; qt < 2; ++qt) {                                          \
        f32x4 c = (f32x4){0.f, 0.f, 0.f, 0.f};                                  \
        c = __builtin_amdgcn_mfma_f32_16x16x32_bf16(kah0, qfh[qt][0], c, 0, 0, 0); \
        c = __builtin_amdgcn_mfma_f32_16x16x32_bf16(kah1, qfh[qt][1], c, 0, 0, 0); \
        c = __builtin_amdgcn_mfma_f32_16x16x32_bf16(kah0, qfl[qt][0], c, 0, 0, 0); \
        c = __builtin_amdgcn_mfma_f32_16x16x32_bf16(kah1, qfl[qt][1], c, 0, 0, 0); \
        c = __builtin_amdgcn_mfma_f32_16x16x32_bf16(kal0, qfh[qt][0], c, 0, 0, 0); \
        c = __builtin_amdgcn_mfma_f32_16x16x32_bf16(kal1, qfh[qt][1], c, 0, 0, 0); \
        (STV)[mt][qt] = c;                                                      \
      }                                                                         \
    }

  // defer-max online softmax for one qt: cross-lane + rescale only on vote fail
  #define SM_QT(QT)                                                             \
    {                                                                           \
      float cm = -1e30f;                                                        \
      _Pragma("unroll")                                                         \
      for (int mt = 0; mt < 4; ++mt)                                            \
        _Pragma("unroll")                                                       \
        for (int r = 0; r < 4; ++r) cm = fmaxf(cm, st[mt][QT][r]);              \
      if (!__all(cm <= m_run[QT] + 8.0f)) {                                     \
        cm = fmaxf(cm, __shfl_xor(cm, 16));                                     \
        cm = fmaxf(cm, __shfl_xor(cm, 32));                                     \
        float mn = fmaxf(cm, m_run[QT]);                                        \
        float alpha = fast_exp2(m_run[QT] - mn);                                \
        m_run[QT] = mn;                                                         \
        l_run[QT] *= alpha;                                                     \
        _Pragma("unroll")                                                       \
        for (int vt = 0; vt < 4; ++vt) acc[QT][vt] = acc[QT][vt] * alpha;       \
      }                                                                         \
      float mn = m_run[QT];                                                     \
      float ssum = 0.f;                                                         \
      _Pragma("unroll")                                                         \
      for (int mt = 0; mt < 4; ++mt) {                                          \
        float p0 = fast_exp2(st[mt][QT][0] - mn);                               \
        float p1 = fast_exp2(st[mt][QT][1] - mn);                               \
        float p2 = fast_exp2(st[mt][QT][2] - mn);                               \
        float p3 = fast_exp2(st[mt][QT][3] - mn);                               \
        ssum += (p0 + p1) + (p2 + p3);                                          \
        union { bf16x4 v; unsigned u2[2]; } pk;                                 \
        pk.u2[0] = pack2_bf16(p0, p1);                                          \
        pk.u2[1] = pack2_bf16(p2, p3);                                          \
        pb[QT][mt] = pk.v;                                                      \
      }                                                                         \
      l_run[QT] += ssum;                                                        \
    }

  #define PV_LOAD(VSP)                                                          \
    _Pragma("unroll")                                                           \
    for (int vt = 0; vt < 4; ++vt)                                              \
      _Pragma("unroll")                                                         \
      for (int mt = 0; mt < 4; ++mt) {                                          \
        int row = vt * 16 + l16;                                                \
        int addr = row * 64 + ((((mt * 2 + (quad >> 1)) ^ (row & 7)) & 7) << 3) + (quad & 1) * 4; \
        va[vt][mt] = *(const bf16x4*)((VSP) + addr);                            \
      }

  #define PV_MFMA                                                               \
    _Pragma("unroll")                                                           \
    for (int vt = 0; vt < 4; ++vt)                                              \
      _Pragma("unroll")                                                         \
      for (int mt = 0; mt < 4; ++mt)                                            \
        _Pragma("unroll")                                                       \
        for (int qt = 0; qt < 2; ++qt)                                          \
          acc[qt][vt] = mfma16x16x16_bf16(va[vt][mt], pb[qt][mt], acc[qt][vt]);

  // prologue
  STAGE_K(0, 0);
  STAGE_V(0, 0);
  STAGE_K(1, 1);
  asm volatile("s_waitcnt vmcnt(0)" ::: "memory");
  __syncthreads();

  f32x4 st[4][2];
  __builtin_amdgcn_s_setprio(1);
  QK_HALF(st, KtH[0], KtL[0], 0);
  QK_HALF(st, KtH[0], KtL[0], 2);
  __builtin_amdgcn_s_setprio(0);

  #pragma unroll 2
  for (int t = 0; t < SEQ / 64 - 1; ++t) {
    const int cb = t & 1, nb = (t + 1) & 1;
    if (t + 2 < SEQ / 64) STAGE_K(cb, t + 2);
    STAGE_V(nb, t + 1);

    const unsigned short* kHn = KtH[nb];
    const unsigned short* kLn = KtL[nb];
    const unsigned short* vS  = Vts[cb];

    bf16x4 pb[2][4];
    bf16x4 va[4][4];
    f32x4 stn[4][2];
    PV_LOAD(vS);            // hoisted: LDS latency hides under softmax + QK
    SM_QT(0);
    __builtin_amdgcn_s_setprio(1);
    QK_HALF(stn, kHn, kLn, 0);
    __builtin_amdgcn_s_setprio(0);
    SM_QT(1);
    __builtin_amdgcn_s_setprio(1);
    QK_HALF(stn, kHn, kLn, 2);
    PV_MFMA;
    __builtin_amdgcn_s_setprio(0);

    #pragma unroll
    for (int mt = 0; mt < 4; ++mt)
      #pragma unroll
      for (int qt = 0; qt < 2; ++qt) st[mt][qt] = stn[mt][qt];

    asm volatile("s_waitcnt vmcnt(0)" ::: "memory");
    __syncthreads();
  }

  // tail: softmax + PV of the last tile
  {
    bf16x4 pb[2][4];
    bf16x4 va[4][4];
    PV_LOAD(Vts[(SEQ / 64 - 1) & 1]);
    SM_QT(0);
    SM_QT(1);
    PV_MFMA;
  }
  #undef STAGE_K
  #undef STAGE_V
  #undef QK_HALF
  #undef SM_QT
  #undef PV_LOAD
  #undef PV_MFMA

  // epilogue: reduce per-lane l partials across quads, then store ctx
  int h = bh & 15, b = bh >> 4;
  #pragma unroll
  for (int qt = 0; qt < 2; ++qt) {
    float lt = l_run[qt];
    lt += __shfl_xor(lt, 16);
    lt += __shfl_xor(lt, 32);
    float inv = 1.0f / lt;
    int bs = b * SEQ + q0 + w * 32 + qt * 16 + l16;
    #pragma unroll
    for (int vt = 0; vt < 4; ++vt) {
      union { bf16x4 v; unsigned u2[2]; } pk;
      pk.u2[0] = pack2_bf16(acc[qt][vt][0] * inv, acc[qt][vt][1] * inv);
      pk.u2[1] = pack2_bf16(acc[qt][vt][2] * inv, acc[qt][vt][3] * inv);
      *(bf16x4*)(ctx + (size_t)bs * DM + h * 64 + vt * 16 + quad * 4) = pk.v;
    }
  }
}

// ---------- GEMM2: ctx @ WoT^T -> fp32 out ----------
__global__ __launch_bounds__(256, 2)
void gemm_out(const unsigned short* __restrict__ A, const unsigned short* __restrict__ Bt,
              float* __restrict__ out) {
  __shared__ unsigned short As[64 * 64];     // 8 KB
  __shared__ unsigned short Bs[128 * 64];    // 16 KB
  const int tid = threadIdx.x;
  const int w = tid >> 6, lane = tid & 63;
  const int quad = lane >> 4, l16 = lane & 15;
  const int wm = w >> 1, wn = w & 1;
  const int bn = blockIdx.x, bm = blockIdx.y;

  f32x4 acc[2][4];
  #pragma unroll
  for (int i = 0; i < 2; ++i)
    #pragma unroll
    for (int j = 0; j < 4; ++j) acc[i][j] = (f32x4){0.f, 0.f, 0.f, 0.f};

  const int r8 = lane >> 3, c8 = lane & 7;
  const int cs = c8 ^ r8;
  const size_t offA = (size_t)(bm * 64 + w * 16 + r8) * DM + cs * 8;
  const size_t offB = (size_t)(bn * 128 + w * 32 + r8) * DM + cs * 8;

  for (int kk = 0; kk < DM / 64; ++kk) {
    #pragma unroll
    for (int ps = 0; ps < 2; ++ps)
      stage16(A + offA + kk * 64 + ps * 8 * DM, As + (w * 16 + ps * 8) * 64, lane);
    #pragma unroll
    for (int ps = 0; ps < 4; ++ps)
      stage16(Bt + offB + kk * 64 + ps * 8 * DM, Bs + (w * 32 + ps * 8) * 64, lane);
    asm volatile("s_waitcnt vmcnt(0)" ::: "memory");
    __syncthreads();
    #pragma unroll
    for (int ks = 0; ks < 2; ++ks) {
      bf16x8 af[2], bfr[4];
      #pragma unroll
      for (int mt = 0; mt < 2; ++mt) {
        int row = wm * 32 + mt * 16 + l16;
        af[mt] = *(const bf16x8*)(As + row * 64 + ((((ks * 4 + quad) ^ (row & 7)) & 7) << 3));
      }
      #pragma unroll
      for (int nt = 0; nt < 4; ++nt) {
        int row = wn * 64 + nt * 16 + l16;
        bfr[nt] = *(const bf16x8*)(Bs + row * 64 + ((((ks * 4 + quad) ^ (row & 7)) & 7) << 3));
      }
      #pragma unroll
      for (int mt = 0; mt < 2; ++mt)
        #pragma unroll
        for (int nt = 0; nt < 4; ++nt)
          acc[mt][nt] = __builtin_amdgcn_mfma_f32_16x16x32_bf16(af[mt], bfr[nt], acc[mt][nt], 0, 0, 0);
    }
    __syncthreads();
  }

  #pragma unroll
  for (int mt = 0; mt < 2; ++mt) {
    int m_g = bm * 64 + wm * 32 + mt * 16 + quad * 4;
    #pragma unroll
    for (int nt = 0; nt < 4; ++nt) {
      int n_g = bn * 128 + wn * 64 + nt * 16 + l16;
      #pragma unroll
      for (int r = 0; r < 4; ++r)
        out[(size_t)(m_g + r) * DM + n_g] = acc[mt][nt][r];
    }
  }
}

// ---------- launch ----------
extern "C" void kernel_launch(void* const* d_in, const int* in_sizes, int n_in,
                              void* d_out, int out_size, void* d_ws, size_t ws_size,
                              hipStream_t stream) {
  const float* x  = (const float*)d_in[0];
  const float* Wk = (const float*)d_in[1];
  const float* Wq = (const float*)d_in[2];
  const float* Wv = (const float*)d_in[3];
  const float* Wo = (const float*)d_in[4];
  float* out = (float*)d_out;

  unsigned short* xh  = (unsigned short*)d_ws;                  // [4096][1024]
  unsigned short* xl  = xh  + (size_t)BS * DM;
  unsigned short* Wh  = xl  + (size_t)BS * DM;                  // [3072][1024]
  unsigned short* Wl  = Wh  + (size_t)3 * DM * DM;
  unsigned short* WoT = Wl  + (size_t)3 * DM * DM;              // [1024][1024]
  unsigned short* Qh  = WoT + (size_t)DM * DM;                  // [32][2048][64]
  unsigned short* Ql  = Qh  + (size_t)BHD * SEQ * DKV;
  unsigned short* Kh  = Ql  + (size_t)BHD * SEQ * DKV;
  unsigned short* Kl  = Kh  + (size_t)BHD * SEQ * DKV;
  unsigned short* Vtb = Kl  + (size_t)BHD * SEQ * DKV;          // [32][64][2048]
  unsigned short* ctx = Vtb + (size_t)BHD * SEQ * DKV;          // [4096][1024]

  prep<<<3072, 256, 0, stream>>>(x, Wq, Wk, Wv, Wo, xh, xl, Wh, Wl, WoT);
  gemm_qkv<<<1024, 256, 0, stream>>>(xh, xl, Wh, Wl, Qh, Ql, Kh, Kl, Vtb);
  flash<<<dim3(BHD, SEQ / 128), 256, 0, stream>>>(Qh, Ql, Kh, Kl, Vtb, ctx);
  gemm_out<<<dim3(8, 64), 256, 0, stream>>>(ctx, WoT, out);
}

// Round 8
// 235.020 us; speedup vs baseline: 1.0635x; 1.0635x over previous
//
#include <hip/hip_runtime.h>
#include <hip/hip_bf16.h>
#include <stdint.h>

#define DM   1024
#define DKV  64
#define HEADS 16
#define BATCH 2
#define SEQ  2048
#define BS   (BATCH*SEQ)    // 4096
#define BHD  (BATCH*HEADS)  // 32

typedef __attribute__((ext_vector_type(8))) short bf16x8;
typedef __attribute__((ext_vector_type(4))) short bf16x4;
typedef __attribute__((ext_vector_type(4))) float f32x4;

// ---------- helpers ----------
__device__ inline unsigned fb(float f) { union { float f; unsigned u; } v; v.f = f; return v.u; }

__device__ inline unsigned short bf16_rtn(float f) {
  unsigned u = fb(f);
  unsigned r = u + 0x7fffu + ((u >> 16) & 1u);
  return (unsigned short)(r >> 16);
}
__device__ inline float bf16_to_f(unsigned short h) {
  union { unsigned u; float f; } v; v.u = ((unsigned)h) << 16; return v.f;
}
// split x ≈ hi + lo, |lo| <= 2^-9 |x|, residual ~2^-18
__device__ inline void split_bf16(float x, unsigned short& hi, unsigned short& lo) {
  hi = bf16_rtn(x);
  lo = bf16_rtn(x - bf16_to_f(hi));
}
// pack two fp32 -> two bf16 (round-half-up) in one dword via v_perm_b32
__device__ inline unsigned pack2_bf16(float lo_elem, float hi_elem) {
  return __builtin_amdgcn_perm(fb(hi_elem) + 0x8000u, fb(lo_elem) + 0x8000u, 0x07060302u);
}

__device__ inline float fast_exp2(float x) {
#if __has_builtin(__builtin_amdgcn_exp2f)
  return __builtin_amdgcn_exp2f(x);
#else
  return exp2f(x);
#endif
}

__device__ inline float max3f(float a, float b, float c) {
  return fmaxf(fmaxf(a, b), c);   // clang fuses to v_max3_f32
}

__device__ inline f32x4 mfma16x16x16_bf16(bf16x4 a, bf16x4 b, f32x4 c) {
#if __has_builtin(__builtin_amdgcn_mfma_f32_16x16x16bf16_1k)
  return __builtin_amdgcn_mfma_f32_16x16x16bf16_1k(a, b, c, 0, 0, 0);
#else
  asm volatile("v_mfma_f32_16x16x16_bf16 %0, %1, %2, %0" : "+v"(c) : "v"(a), "v"(b));
  return c;
#endif
}

// stage 16B/lane: async direct-to-LDS (dest = wave-uniform base + lane*16)
__device__ inline void stage16(const unsigned short* g, unsigned short* lds_base, int lane) {
#if __has_builtin(__builtin_amdgcn_global_load_lds)
  __builtin_amdgcn_global_load_lds((__attribute__((address_space(1))) void*)(g),
                                   (__attribute__((address_space(3))) void*)(lds_base),
                                   16, 0, 0);
#else
  *(bf16x8*)(lds_base + lane * 8) = *(const bf16x8*)g;
#endif
}

// XOR-swizzled LDS index for a 64-col bf16 tile (8 chunks of 8 shorts per row)
__device__ inline int swz(int row, int chunk) {
  return row * 64 + (((chunk ^ (row & 7)) & 7) << 3);
}

// ---------- fused prep: blocks [0,2048) cvt_x_split, [2048,2816) pack_qkv_split,
// ---------- [2816,3072) pack_wo.
__global__ void prep(const float* __restrict__ x,
                     const float* __restrict__ Wq, const float* __restrict__ Wk,
                     const float* __restrict__ Wv, const float* __restrict__ Wo,
                     unsigned short* __restrict__ xh, unsigned short* __restrict__ xl,
                     unsigned short* __restrict__ Wh, unsigned short* __restrict__ Wl,
                     unsigned short* __restrict__ WoT) {
  __shared__ float tile[64][65];
  const int bid = blockIdx.x;
  const int t = threadIdx.x;

  if (bid < 2048) {
    // ---- cvt_x_split ----
    int i = (bid * 256 + t) * 8;
    bf16x8 oh, ol;
    #pragma unroll
    for (int j = 0; j < 8; ++j) {
      unsigned short hi, lo;
      split_bf16(x[i + j], hi, lo);
      oh[j] = (short)hi; ol[j] = (short)lo;
    }
    *(bf16x8*)(xh + i) = oh;
    *(bf16x8*)(xl + i) = ol;
    return;
  }
  if (bid < 2816) {
    // ---- pack_qkv_split: b2 = p*256 + h*16 + mt ----
    int b2 = bid - 2048;
    int p = b2 >> 8, h = (b2 >> 4) & 15, mt = b2 & 15;
    const float* W = (p == 0) ? Wq : (p == 1) ? Wk : Wv;
    const float* src = W + (size_t)h * (DM * DKV);
    int m0 = mt * 64;
    #pragma unroll
    for (int pass = 0; pass < 16; ++pass) {
      int row = pass * 4 + (t >> 6), col = t & 63;
      tile[row][col] = src[(size_t)(m0 + row) * DKV + col];
    }
    __syncthreads();
    int cbase = p * 1024 + h * 64;
    #pragma unroll
    for (int pass = 0; pass < 16; ++pass) {
      int krow = pass * 4 + (t >> 6), mcol = t & 63;
      unsigned short hi, lo;
      split_bf16(tile[mcol][krow], hi, lo);
      size_t idx = (size_t)(cbase + krow) * DM + m0 + mcol;
      Wh[idx] = hi; Wl[idx] = lo;
    }
    return;
  }
  {
    // ---- pack_wo: b3 = ib*16 + jb ----
    int b3 = bid - 2816;
    int ib = b3 >> 4, jb = b3 & 15;
    #pragma unroll
    for (int pass = 0; pass < 16; ++pass) {
      int row = pass * 4 + (t >> 6), col = t & 63;
      tile[row][col] = Wo[(size_t)(ib * 64 + row) * DM + jb * 64 + col];
    }
    __syncthreads();
    #pragma unroll
    for (int pass = 0; pass < 16; ++pass) {
      int a = pass * 4 + (t >> 6), b = t & 63;
      WoT[(size_t)(jb * 64 + a) * DM + ib * 64 + b] = bf16_rtn(tile[b][a]);
    }
  }
}

// ---------- fused gemm_qkv: blocks 0..511 do x@Wqk^T (split, 128x128), ----------
// ---------- blocks 512..1023 do x@Wv^T (64x128) -> Vt.                 ----------
__global__ __launch_bounds__(256, 2)
void gemm_qkv(const unsigned short* __restrict__ Ah, const unsigned short* __restrict__ Al,
              const unsigned short* __restrict__ Bh, const unsigned short* __restrict__ Bl,
              unsigned short* __restrict__ Qh, unsigned short* __restrict__ Ql,
              unsigned short* __restrict__ Kh, unsigned short* __restrict__ Kl,
              unsigned short* __restrict__ Vt) {
  __shared__ unsigned short smem[32768];   // 64 KB
  const int tid = threadIdx.x;
  const int w = tid >> 6, lane = tid & 63;
  const int quad = lane >> 4, l16 = lane & 15;
  const int wm = w >> 1, wn = w & 1;
  const int bid = blockIdx.x;
  const int r8 = lane >> 3, c8 = lane & 7;
  const int cs = c8 ^ r8;

  if (bid < 512) {
    // ---- QK half: tile 128x128, BK=64, split-precision (3 MFMA/frag) ----
    unsigned short* AsH = smem;            // 8192 shorts
    unsigned short* AsL = smem + 8192;
    unsigned short* BsH = smem + 16384;
    unsigned short* BsL = smem + 24576;
    const int bn = bid & 15, bm = bid >> 4;

    f32x4 acc[4][4];
    #pragma unroll
    for (int i = 0; i < 4; ++i)
      #pragma unroll
      for (int j = 0; j < 4; ++j) acc[i][j] = (f32x4){0.f, 0.f, 0.f, 0.f};

    const size_t offA = (size_t)(bm * 128 + w * 32 + r8) * DM + cs * 8;
    const size_t offB = (size_t)(bn * 128 + w * 32 + r8) * DM + cs * 8;

    for (int kk = 0; kk < DM / 64; ++kk) {
      #pragma unroll
      for (int ps = 0; ps < 4; ++ps) {
        stage16(Ah + offA + kk * 64 + ps * 8 * DM, AsH + (w * 32 + ps * 8) * 64, lane);
        stage16(Al + offA + kk * 64 + ps * 8 * DM, AsL + (w * 32 + ps * 8) * 64, lane);
        stage16(Bh + offB + kk * 64 + ps * 8 * DM, BsH + (w * 32 + ps * 8) * 64, lane);
        stage16(Bl + offB + kk * 64 + ps * 8 * DM, BsL + (w * 32 + ps * 8) * 64, lane);
      }
      asm volatile("s_waitcnt vmcnt(0)" ::: "memory");
      __syncthreads();
      #pragma unroll
      for (int ks = 0; ks < 2; ++ks) {
        bf16x8 afh[4], afl[4], bfh[4], bfl[4];
        #pragma unroll
        for (int mt = 0; mt < 4; ++mt) {
          int row = wm * 64 + mt * 16 + l16;
          int ad = row * 64 + ((((ks * 4 + quad) ^ (row & 7)) & 7) << 3);
          afh[mt] = *(const bf16x8*)(AsH + ad);
          afl[mt] = *(const bf16x8*)(AsL + ad);
        }
        #pragma unroll
        for (int nt = 0; nt < 4; ++nt) {
          int row = wn * 64 + nt * 16 + l16;
          int ad = row * 64 + ((((ks * 4 + quad) ^ (row & 7)) & 7) << 3);
          bfh[nt] = *(const bf16x8*)(BsH + ad);
          bfl[nt] = *(const bf16x8*)(BsL + ad);
        }
        #pragma unroll
        for (int mt = 0; mt < 4; ++mt)
          #pragma unroll
          for (int nt = 0; nt < 4; ++nt) {
            acc[mt][nt] = __builtin_amdgcn_mfma_f32_16x16x32_bf16(afh[mt], bfh[nt], acc[mt][nt], 0, 0, 0);
            acc[mt][nt] = __builtin_amdgcn_mfma_f32_16x16x32_bf16(afh[mt], bfl[nt], acc[mt][nt], 0, 0, 0);
            acc[mt][nt] = __builtin_amdgcn_mfma_f32_16x16x32_bf16(afl[mt], bfh[nt], acc[mt][nt], 0, 0, 0);
          }
      }
      __syncthreads();
    }

    const float SCL = 0.18033688011112042f;  // (1/sqrt(64)) * log2(e), folded into Q
    #pragma unroll
    for (int mt = 0; mt < 4; ++mt) {
      int m_g = bm * 128 + wm * 64 + mt * 16 + quad * 4;
      #pragma unroll
      for (int nt = 0; nt < 4; ++nt) {
        int n_g = bn * 128 + wn * 64 + nt * 16 + l16;
        int p = n_g >> 10, h = (n_g >> 6) & 15, k = n_g & 63;
        #pragma unroll
        for (int r = 0; r < 4; ++r) {
          int row = m_g + r;
          int b = row >> 11, s = row & 2047;
          int bh = b * HEADS + h;
          float v = acc[mt][nt][r];
          size_t idx = ((size_t)(bh * SEQ + s)) * DKV + k;
          unsigned short hi, lo;
          if (p == 0) {
            split_bf16(v * SCL, hi, lo);
            Qh[idx] = hi; Ql[idx] = lo;
          } else {
            split_bf16(v, hi, lo);
            Kh[idx] = hi; Kl[idx] = lo;
          }
        }
      }
    }
  } else {
    // ---- V half: plain bf16, tile 64x128 -> Vt transposed ----
    unsigned short* As = smem;             // 4096 shorts
    unsigned short* Bs = smem + 4096;      // 8192 shorts
    const int vid = bid - 512;
    const int bn = vid & 7, bm = vid >> 3;
    const unsigned short* Bt = Bh + (size_t)2048 * DM;   // V weight rows of WcatT (hi)

    f32x4 acc[2][4];
    #pragma unroll
    for (int i = 0; i < 2; ++i)
      #pragma unroll
      for (int j = 0; j < 4; ++j) acc[i][j] = (f32x4){0.f, 0.f, 0.f, 0.f};

    const size_t offA = (size_t)(bm * 64 + w * 16 + r8) * DM + cs * 8;
    const size_t offB = (size_t)(bn * 128 + w * 32 + r8) * DM + cs * 8;

    for (int kk = 0; kk < DM / 64; ++kk) {
      #pragma unroll
      for (int ps = 0; ps < 2; ++ps)
        stage16(Ah + offA + kk * 64 + ps * 8 * DM, As + (w * 16 + ps * 8) * 64, lane);
      #pragma unroll
      for (int ps = 0; ps < 4; ++ps)
        stage16(Bt + offB + kk * 64 + ps * 8 * DM, Bs + (w * 32 + ps * 8) * 64, lane);
      asm volatile("s_waitcnt vmcnt(0)" ::: "memory");
      __syncthreads();
      #pragma unroll
      for (int ks = 0; ks < 2; ++ks) {
        bf16x8 af[2], bfr[4];
        #pragma unroll
        for (int mt = 0; mt < 2; ++mt) {
          int row = wm * 32 + mt * 16 + l16;
          af[mt] = *(const bf16x8*)(As + row * 64 + ((((ks * 4 + quad) ^ (row & 7)) & 7) << 3));
        }
        #pragma unroll
        for (int nt = 0; nt < 4; ++nt) {
          int row = wn * 64 + nt * 16 + l16;
          bfr[nt] = *(const bf16x8*)(Bs + row * 64 + ((((ks * 4 + quad) ^ (row & 7)) & 7) << 3));
        }
        #pragma unroll
        for (int mt = 0; mt < 2; ++mt)
          #pragma unroll
          for (int nt = 0; nt < 4; ++nt)
            acc[mt][nt] = __builtin_amdgcn_mfma_f32_16x16x32_bf16(af[mt], bfr[nt], acc[mt][nt], 0, 0, 0);
      }
      __syncthreads();
    }

    #pragma unroll
    for (int mt = 0; mt < 2; ++mt) {
      int m_g = bm * 64 + wm * 32 + mt * 16 + quad * 4;
      #pragma unroll
      for (int nt = 0; nt < 4; ++nt) {
        int n_g = bn * 128 + wn * 64 + nt * 16 + l16;   // 0..1023 within V block
        int h = n_g >> 6, k = n_g & 63;
        #pragma unroll
        for (int r = 0; r < 4; ++r) {
          int row = m_g + r;
          int b = row >> 11, s = row & 2047;
          int bh = b * HEADS + h;
          Vt[((size_t)(bh * DKV + k)) * SEQ + s] = bf16_rtn(acc[mt][nt][r]);
        }
      }
    }
  }
}

// ---------- flash: pipelined + defer-max softmax (r6 form; best measured 87.2us) ----------
// 256 threads, 4 waves, 32 q-rows/wave (qt=2); K hi/lo + V double-buffered (48 KB).
// Defer-max (T13): keep stale m_run while per-lane max within THR=8 (wave vote).
// Common case: no shfl reduces, no rescale; l_run is a PER-LANE partial reduced
// once in the epilogue. QK(t+1) striped between softmax(t) halves; setprio (T5).
// NOTE (r7 post-mortem): do NOT hoist PV loads into registers — raises VGPR
// 92->108 and regresses 4us; the compiler's own schedule is better.
__global__ __launch_bounds__(256, 2)
void flash(const unsigned short* __restrict__ Qh, const unsigned short* __restrict__ Ql,
           const unsigned short* __restrict__ Kh, const unsigned short* __restrict__ Kl,
           const unsigned short* __restrict__ Vt, unsigned short* __restrict__ ctx) {
  __shared__ unsigned short KtH[2][64 * 64], KtL[2][64 * 64], Vts[2][64 * 64];
  const int tid = threadIdx.x;
  const int w = tid >> 6, lane = tid & 63, quad = lane >> 4, l16 = lane & 15;
  const int bh = blockIdx.x;
  const int q0 = blockIdx.y * 128;

  // Q B-frags (scaled by SCL already): [n=q][k=d], split hi/lo
  bf16x8 qfh[2][2], qfl[2][2];
  #pragma unroll
  for (int qt = 0; qt < 2; ++qt) {
    int qrow = q0 + w * 32 + qt * 16 + l16;
    size_t base = ((size_t)(bh * SEQ + qrow)) * DKV + quad * 8;
    qfh[qt][0] = *(const bf16x8*)(Qh + base);
    qfh[qt][1] = *(const bf16x8*)(Qh + base + 32);
    qfl[qt][0] = *(const bf16x8*)(Ql + base);
    qfl[qt][1] = *(const bf16x8*)(Ql + base + 32);
  }

  float m_run[2] = {-1e30f, -1e30f};
  float l_run[2] = {0.f, 0.f};          // PER-LANE partial sums
  f32x4 acc[2][4];
  #pragma unroll
  for (int qt = 0; qt < 2; ++qt)
    #pragma unroll
    for (int vt = 0; vt < 4; ++vt) acc[qt][vt] = (f32x4){0.f, 0.f, 0.f, 0.f};

  const int srow = w * 16 + (lane >> 3);
  const int csrc = (lane & 7) ^ (lane >> 3);
  const unsigned short* kh_src = Kh + ((size_t)(bh * SEQ) + srow) * DKV + csrc * 8;
  const unsigned short* kl_src = Kl + ((size_t)(bh * SEQ) + srow) * DKV + csrc * 8;
  const unsigned short* v_src  = Vt + ((size_t)(bh * DKV) + srow) * SEQ + csrc * 8;

  #define STAGE_K(buf, kt0)                                                     \
    do {                                                                        \
      unsigned short* dH = &KtH[buf][(w * 16) * 64];                            \
      unsigned short* dL = &KtL[buf][(w * 16) * 64];                            \
      stage16(kh_src + (size_t)(kt0) * 64 * DKV,           dH,       lane);     \
      stage16(kh_src + (size_t)(kt0) * 64 * DKV + 8 * DKV, dH + 512, lane);     \
      stage16(kl_src + (size_t)(kt0) * 64 * DKV,           dL,       lane);     \
      stage16(kl_src + (size_t)(kt0) * 64 * DKV + 8 * DKV, dL + 512, lane);     \
    } while (0)
  #define STAGE_V(buf, kt0)                                                     \
    do {                                                                        \
      unsigned short* dV = &Vts[buf][(w * 16) * 64];                            \
      stage16(v_src + (kt0) * 64,           dV,       lane);                    \
      stage16(v_src + (kt0) * 64 + 8 * SEQ, dV + 512, lane);                    \
    } while (0)

  #define QK_HALF(STV, KHP, KLP, MT0)                                           \
    _Pragma("unroll")                                                           \
    for (int mt = (MT0); mt < (MT0) + 2; ++mt) {                                \
      int rowA = mt * 16 + l16;                                                 \
      bf16x8 kah0 = *(const bf16x8*)((KHP) + swz(rowA, quad));                  \
      bf16x8 kah1 = *(const bf16x8*)((KHP) + swz(rowA, quad + 4));              \
      bf16x8 kal0 = *(const bf16x8*)((KLP) + swz(rowA, quad));                  \
      bf16x8 kal1 = *(const bf16x8*)((KLP) + swz(rowA, quad + 4));              \
      _Pragma("unroll")                                                         \
      for (int qt = 0; qt < 2; ++qt) {                                          \
        f32x4 c = (f32x4){0.f, 0.f, 0.f, 0.f};                                  \
        c = __builtin_amdgcn_mfma_f32_16x16x32_bf16(kah0, qfh[qt][0], c, 0, 0, 0); \
        c = __builtin_amdgcn_mfma_f32_16x16x32_bf16(kah1, qfh[qt][1], c, 0, 0, 0); \
        c = __builtin_amdgcn_mfma_f32_16x16x32_bf16(kah0, qfl[qt][0], c, 0, 0, 0); \
        c = __builtin_amdgcn_mfma_f32_16x16x32_bf16(kah1, qfl[qt][1], c, 0, 0, 0); \
        c = __builtin_amdgcn_mfma_f32_16x16x32_bf16(kal0, qfh[qt][0], c, 0, 0, 0); \
        c = __builtin_amdgcn_mfma_f32_16x16x32_bf16(kal1, qfh[qt][1], c, 0, 0, 0); \
        (STV)[mt][qt] = c;                                                      \
      }                                                                         \
    }

  // defer-max online softmax for one qt; balanced v_max3 tree for the 16-way max
  #define SM_QT(QT)                                                             \
    {                                                                           \
      float x0 = max3f(st[0][QT][0], st[0][QT][1], st[0][QT][2]);               \
      float x1 = max3f(st[0][QT][3], st[1][QT][0], st[1][QT][1]);               \
      float x2 = max3f(st[1][QT][2], st[1][QT][3], st[2][QT][0]);               \
      float x3 = max3f(st[2][QT][1], st[2][QT][2], st[2][QT][3]);               \
      float x4 = max3f(st[3][QT][0], st[3][QT][1], st[3][QT][2]);               \
      float cm = fmaxf(max3f(x0, x1, x2), max3f(x3, x4, st[3][QT][3]));         \
      if (!__all(cm <= m_run[QT] + 8.0f)) {                                     \
        cm = fmaxf(cm, __shfl_xor(cm, 16));                                     \
        cm = fmaxf(cm, __shfl_xor(cm, 32));                                     \
        float mn = fmaxf(cm, m_run[QT]);                                        \
        float alpha = fast_exp2(m_run[QT] - mn);                                \
        m_run[QT] = mn;                                                         \
        l_run[QT] *= alpha;                                                     \
        _Pragma("unroll")                                                       \
        for (int vt = 0; vt < 4; ++vt) acc[QT][vt] = acc[QT][vt] * alpha;       \
      }                                                                         \
      float mn = m_run[QT];                                                     \
      float ssum = 0.f;                                                         \
      _Pragma("unroll")                                                         \
      for (int mt = 0; mt < 4; ++mt) {                                          \
        float p0 = fast_exp2(st[mt][QT][0] - mn);                               \
        float p1 = fast_exp2(st[mt][QT][1] - mn);                               \
        float p2 = fast_exp2(st[mt][QT][2] - mn);                               \
        float p3 = fast_exp2(st[mt][QT][3] - mn);                               \
        ssum += (p0 + p1) + (p2 + p3);                                          \
        union { bf16x4 v; unsigned u2[2]; } pk;                                 \
        pk.u2[0] = pack2_bf16(p0, p1);                                          \
        pk.u2[1] = pack2_bf16(p2, p3);                                          \
        pb[QT][mt] = pk.v;                                                      \
      }                                                                         \
      l_run[QT] += ssum;                                                        \
    }

  #define PV_ALL(VSP)                                                           \
    _Pragma("unroll")                                                           \
    for (int vt = 0; vt < 4; ++vt)                                              \
      _Pragma("unroll")                                                         \
      for (int mt = 0; mt < 4; ++mt) {                                          \
        int row = vt * 16 + l16;                                                \
        int addr = row * 64 + ((((mt * 2 + (quad >> 1)) ^ (row & 7)) & 7) << 3) + (quad & 1) * 4; \
        bf16x4 va = *(const bf16x4*)((VSP) + addr);                             \
        _Pragma("unroll")                                                       \
        for (int qt = 0; qt < 2; ++qt)                                          \
          acc[qt][vt] = mfma16x16x16_bf16(va, pb[qt][mt], acc[qt][vt]);         \
      }

  // prologue
  STAGE_K(0, 0);
  STAGE_V(0, 0);
  STAGE_K(1, 1);
  asm volatile("s_waitcnt vmcnt(0)" ::: "memory");
  __syncthreads();

  f32x4 st[4][2];
  __builtin_amdgcn_s_setprio(1);
  QK_HALF(st, KtH[0], KtL[0], 0);
  QK_HALF(st, KtH[0], KtL[0], 2);
  __builtin_amdgcn_s_setprio(0);

  #pragma unroll 2
  for (int t = 0; t < SEQ / 64 - 1; ++t) {
    const int cb = t & 1, nb = (t + 1) & 1;
    if (t + 2 < SEQ / 64) STAGE_K(cb, t + 2);
    STAGE_V(nb, t + 1);

    const unsigned short* kHn = KtH[nb];
    const unsigned short* kLn = KtL[nb];
    const unsigned short* vS  = Vts[cb];

    bf16x4 pb[2][4];
    f32x4 stn[4][2];
    SM_QT(0);
    __builtin_amdgcn_s_setprio(1);
    QK_HALF(stn, kHn, kLn, 0);
    __builtin_amdgcn_s_setprio(0);
    SM_QT(1);
    __builtin_amdgcn_s_setprio(1);
    QK_HALF(stn, kHn, kLn, 2);
    PV_ALL(vS);
    __builtin_amdgcn_s_setprio(0);

    #pragma unroll
    for (int mt = 0; mt < 4; ++mt)
      #pragma unroll
      for (int qt = 0; qt < 2; ++qt) st[mt][qt] = stn[mt][qt];

    asm volatile("s_waitcnt vmcnt(0)" ::: "memory");
    __syncthreads();
  }

  // tail: softmax + PV of the last tile
  {
    bf16x4 pb[2][4];
    SM_QT(0);
    SM_QT(1);
    PV_ALL(Vts[(SEQ / 64 - 1) & 1]);
  }
  #undef STAGE_K
  #undef STAGE_V
  #undef QK_HALF
  #undef SM_QT
  #undef PV_ALL

  // epilogue: reduce per-lane l partials across quads, then store ctx
  int h = bh & 15, b = bh >> 4;
  #pragma unroll
  for (int qt = 0; qt < 2; ++qt) {
    float lt = l_run[qt];
    lt += __shfl_xor(lt, 16);
    lt += __shfl_xor(lt, 32);
    float inv = 1.0f / lt;
    int bs = b * SEQ + q0 + w * 32 + qt * 16 + l16;
    #pragma unroll
    for (int vt = 0; vt < 4; ++vt) {
      union { bf16x4 v; unsigned u2[2]; } pk;
      pk.u2[0] = pack2_bf16(acc[qt][vt][0] * inv, acc[qt][vt][1] * inv);
      pk.u2[1] = pack2_bf16(acc[qt][vt][2] * inv, acc[qt][vt][3] * inv);
      *(bf16x4*)(ctx + (size_t)bs * DM + h * 64 + vt * 16 + quad * 4) = pk.v;
    }
  }
}

// ---------- GEMM2: ctx @ WoT^T -> fp32 out ----------
__global__ __launch_bounds__(256, 2)
void gemm_out(const unsigned short* __restrict__ A, const unsigned short* __restrict__ Bt,
              float* __restrict__ out) {
  __shared__ unsigned short As[64 * 64];     // 8 KB
  __shared__ unsigned short Bs[128 * 64];    // 16 KB
  const int tid = threadIdx.x;
  const int w = tid >> 6, lane = tid & 63;
  const int quad = lane >> 4, l16 = lane & 15;
  const int wm = w >> 1, wn = w & 1;
  const int bn = blockIdx.x, bm = blockIdx.y;

  f32x4 acc[2][4];
  #pragma unroll
  for (int i = 0; i < 2; ++i)
    #pragma unroll
    for (int j = 0; j < 4; ++j) acc[i][j] = (f32x4){0.f, 0.f, 0.f, 0.f};

  const int r8 = lane >> 3, c8 = lane & 7;
  const int cs = c8 ^ r8;
  const size_t offA = (size_t)(bm * 64 + w * 16 + r8) * DM + cs * 8;
  const size_t offB = (size_t)(bn * 128 + w * 32 + r8) * DM + cs * 8;

  for (int kk = 0; kk < DM / 64; ++kk) {
    #pragma unroll
    for (int ps = 0; ps < 2; ++ps)
      stage16(A + offA + kk * 64 + ps * 8 * DM, As + (w * 16 + ps * 8) * 64, lane);
    #pragma unroll
    for (int ps = 0; ps < 4; ++ps)
      stage16(Bt + offB + kk * 64 + ps * 8 * DM, Bs + (w * 32 + ps * 8) * 64, lane);
    asm volatile("s_waitcnt vmcnt(0)" ::: "memory");
    __syncthreads();
    #pragma unroll
    for (int ks = 0; ks < 2; ++ks) {
      bf16x8 af[2], bfr[4];
      #pragma unroll
      for (int mt = 0; mt < 2; ++mt) {
        int row = wm * 32 + mt * 16 + l16;
        af[mt] = *(const bf16x8*)(As + row * 64 + ((((ks * 4 + quad) ^ (row & 7)) & 7) << 3));
      }
      #pragma unroll
      for (int nt = 0; nt < 4; ++nt) {
        int row = wn * 64 + nt * 16 + l16;
        bfr[nt] = *(const bf16x8*)(Bs + row * 64 + ((((ks * 4 + quad) ^ (row & 7)) & 7) << 3));
      }
      #pragma unroll
      for (int mt = 0; mt < 2; ++mt)
        #pragma unroll
        for (int nt = 0; nt < 4; ++nt)
          acc[mt][nt] = __builtin_amdgcn_mfma_f32_16x16x32_bf16(af[mt], bfr[nt], acc[mt][nt], 0, 0, 0);
    }
    __syncthreads();
  }

  #pragma unroll
  for (int mt = 0; mt < 2; ++mt) {
    int m_g = bm * 64 + wm * 32 + mt * 16 + quad * 4;
    #pragma unroll
    for (int nt = 0; nt < 4; ++nt) {
      int n_g = bn * 128 + wn * 64 + nt * 16 + l16;
      #pragma unroll
      for (int r = 0; r < 4; ++r)
        out[(size_t)(m_g + r) * DM + n_g] = acc[mt][nt][r];
    }
  }
}

// ---------- launch ----------
extern "C" void kernel_launch(void* const* d_in, const int* in_sizes, int n_in,
                              void* d_out, int out_size, void* d_ws, size_t ws_size,
                              hipStream_t stream) {
  const float* x  = (const float*)d_in[0];
  const float* Wk = (const float*)d_in[1];
  const float* Wq = (const float*)d_in[2];
  const float* Wv = (const float*)d_in[3];
  const float* Wo = (const float*)d_in[4];
  float* out = (float*)d_out;

  unsigned short* xh  = (unsigned short*)d_ws;                  // [4096][1024]
  unsigned short* xl  = xh  + (size_t)BS * DM;
  unsigned short* Wh  = xl  + (size_t)BS * DM;                  // [3072][1024]
  unsigned short* Wl  = Wh  + (size_t)3 * DM * DM;
  unsigned short* WoT = Wl  + (size_t)3 * DM * DM;              // [1024][1024]
  unsigned short* Qh  = WoT + (size_t)DM * DM;                  // [32][2048][64]
  unsigned short* Ql  = Qh  + (size_t)BHD * SEQ * DKV;
  unsigned short* Kh  = Ql  + (size_t)BHD * SEQ * DKV;
  unsigned short* Kl  = Kh  + (size_t)BHD * SEQ * DKV;
  unsigned short* Vtb = Kl  + (size_t)BHD * SEQ * DKV;          // [32][64][2048]
  unsigned short* ctx = Vtb + (size_t)BHD * SEQ * DKV;          // [4096][1024]

  prep<<<3072, 256, 0, stream>>>(x, Wq, Wk, Wv, Wo, xh, xl, Wh, Wl, WoT);
  gemm_qkv<<<1024, 256, 0, stream>>>(xh, xl, Wh, Wl, Qh, Ql, Kh, Kl, Vtb);
  flash<<<dim3(BHD, SEQ / 128), 256, 0, stream>>>(Qh, Ql, Kh, Kl, Vtb, ctx);
  gemm_out<<<dim3(8, 64), 256, 0, stream>>>(ctx, WoT, out);
}